// Round 7
// baseline (321.429 us; speedup 1.0000x reference)
//
#include <hip/hip_runtime.h>
#include <hip/hip_bf16.h>

// Problem constants
#define BB 16
#define TT 1024
#define DD 256
#define NE 512
#define BT 16384   // BB*TT

typedef unsigned short ushort_t;
typedef unsigned long long ull_t;
typedef __attribute__((ext_vector_type(8))) short bf16x8;
typedef __attribute__((ext_vector_type(4))) float f32x4;

#define AS_GLOBAL __attribute__((address_space(1)))
#define AS_SHARED __attribute__((address_space(3)))

static __device__ __forceinline__ ushort_t f2bf(float f) {
    union { float f; unsigned u; } x; x.f = f;
    unsigned r = x.u + 0x7fffu + ((x.u >> 16) & 1u);   // RNE
    return (ushort_t)(r >> 16);
}

// Bijective XCD-chunked swizzle; REQUIRES grid % 8 == 0.
static __device__ __forceinline__ int xcd_swz(int bid, int grid) {
    const int cpx = grid >> 3;            // chunks per XCD
    return (bid & 7) * cpx + (bid >> 3);
}

// ---------------------------------------------------------------------------
// prep_all: one dispatch for all input normalizations (verified R3-R5).
// ---------------------------------------------------------------------------
__global__ __launch_bounds__(256) void prep_all(const float* __restrict__ ks,
                                                const float* __restrict__ keys,
                                                const float* __restrict__ vparams,
                                                ushort_t* __restrict__ ksn_bf,
                                                ushort_t* __restrict__ keys_n_bf,
                                                float* __restrict__ vp_n,
                                                ushort_t* __restrict__ vp_n_bf,
                                                ushort_t* __restrict__ vpnT_bf) {
    const int bid = blockIdx.x;
    const int t = threadIdx.x;
    if (bid < 4096) {
        const int row  = bid * 4 + (t >> 6);
        const int lane = t & 63;
        const float4 v = *(const float4*)(ks + (long long)row * DD + lane * 4);
        float ss = v.x * v.x + v.y * v.y + v.z * v.z + v.w * v.w;
        #pragma unroll
        for (int off = 32; off > 0; off >>= 1) ss += __shfl_down(ss, off, 64);
        ss = __shfl(ss, 0, 64);
        const float inv = 1.0f / fmaxf(sqrtf(ss), 1e-12f);
        ull_t p =
              (ull_t)f2bf(v.x * inv)
            | ((ull_t)f2bf(v.y * inv) << 16)
            | ((ull_t)f2bf(v.z * inv) << 32)
            | ((ull_t)f2bf(v.w * inv) << 48);
        *(ull_t*)(ksn_bf + (long long)row * DD + lane * 4) = p;
    } else {
        const int b2 = bid - 4096;
        const bool is_keys = (b2 < NE);
        const int rr = is_keys ? b2 : b2 - NE;
        const float* src = (is_keys ? keys : vparams) + (long long)rr * DD;
        const float v = src[t];
        float ss = v * v;
        #pragma unroll
        for (int off = 32; off > 0; off >>= 1) ss += __shfl_down(ss, off, 64);
        __shared__ float partial[4];
        const int wave = t >> 6, lane = t & 63;
        if (lane == 0) partial[wave] = ss;
        __syncthreads();
        __shared__ float s_inv;
        if (t == 0) {
            float tot = partial[0] + partial[1] + partial[2] + partial[3];
            s_inv = 1.0f / fmaxf(sqrtf(tot), 1e-12f);
        }
        __syncthreads();
        const float r = v * s_inv;
        const ushort_t b = f2bf(r);
        if (is_keys) {
            keys_n_bf[(long long)rr * DD + t] = b;
        } else {
            vp_n[(long long)rr * DD + t] = r;
            vp_n_bf[(long long)rr * DD + t] = b;
            vpnT_bf[(long long)t * NE + rr] = b;   // [DD][NE] transpose scatter
        }
    }
}

// ---------------------------------------------------------------------------
// mega_gemm: symmetric batched set + flat set, one dispatch (verified R4/R5).
// Grid must be 1088 (= 8 * 136).
// ---------------------------------------------------------------------------
__global__ __launch_bounds__(256) void mega_gemm(const ushort_t* __restrict__ Ab,
                                                 float* __restrict__ Cb,
                                                 const ushort_t* __restrict__ Af,
                                                 const ushort_t* __restrict__ Bf,
                                                 float* __restrict__ Cf) {
    const int swz = xcd_swz(blockIdx.x, 1088);
    const ushort_t *A, *Bm;
    float* C;
    int bm, bn, ldc;
    bool sym;
    if (swz < 576) {
        const int z = swz / 36;
        int tt = swz - z * 36;
        int i = 0;
        while (tt >= 8 - i) { tt -= 8 - i; ++i; }
        const int j = i + tt;
        A  = Ab + (long long)z * TT * DD;
        Bm = A;
        C  = Cb + (long long)z * TT * TT;
        bm = i * 128; bn = j * 128; ldc = TT;
        sym = (i != j);
    } else {
        const int f = swz - 576;
        A = Af; Bm = Bf; C = Cf;
        bm = (f >> 2) * 128; bn = (f & 3) * 128; ldc = NE;
        sym = false;
    }

    __shared__ ushort_t As[2][128 * 32];
    __shared__ ushort_t Bs[2][128 * 32];

    const int tid = threadIdx.x;
    const int wv = tid >> 6;
    const int ln = tid & 63;
    const int srow   = ln >> 2;         // 0..15
    const int schunk = (ln & 3) * 8;    // 0,8,16,24
    const int wm = (wv >> 1) * 64;
    const int wn = (wv & 1) * 64;
    const int fr = ln & 15;
    const int fq = (ln >> 4) * 8;

    f32x4 acc[4][4] = {};

#define MG_STAGE(buf, kk)                                                          \
    {                                                                              \
        _Pragma("unroll")                                                          \
        for (int s = 0; s < 2; ++s) {                                              \
            const int ra = wv * 32 + s * 16;                                       \
            const ushort_t* ga = A + (long long)(bm + ra + srow) * DD + (kk) + schunk; \
            __builtin_amdgcn_global_load_lds((const AS_GLOBAL void*)ga,            \
                (AS_SHARED void*)&As[buf][ra * 32], 16, 0, 0);                     \
            const ushort_t* gb = Bm + (long long)(bn + ra + srow) * DD + (kk) + schunk; \
            __builtin_amdgcn_global_load_lds((const AS_GLOBAL void*)gb,            \
                (AS_SHARED void*)&Bs[buf][ra * 32], 16, 0, 0);                     \
        }                                                                          \
    }

#define MG_COMPUTE(buf)                                                            \
    {                                                                              \
        bf16x8 af[4], bfr[4];                                                      \
        _Pragma("unroll")                                                          \
        for (int i = 0; i < 4; ++i)                                                \
            af[i] = *(const bf16x8*)&As[buf][(wm + i * 16 + fr) * 32 + fq];        \
        _Pragma("unroll")                                                          \
        for (int j = 0; j < 4; ++j)                                                \
            bfr[j] = *(const bf16x8*)&Bs[buf][(wn + j * 16 + fr) * 32 + fq];       \
        _Pragma("unroll")                                                          \
        for (int i = 0; i < 4; ++i)                                                \
            _Pragma("unroll")                                                      \
            for (int j = 0; j < 4; ++j)                                            \
                acc[i][j] = __builtin_amdgcn_mfma_f32_16x16x32_bf16(af[i], bfr[j], acc[i][j], 0, 0, 0); \
    }

    MG_STAGE(0, 0);
    __syncthreads();
    int cur = 0;
    #pragma unroll
    for (int k0 = 32; k0 < DD; k0 += 32) {
        MG_STAGE(cur ^ 1, k0);
        MG_COMPUTE(cur);
        __syncthreads();
        cur ^= 1;
    }
    MG_COMPUTE(cur);

    const int col  = ln & 15;
    const int qrow = (ln >> 4) * 4;
    #pragma unroll
    for (int i = 0; i < 4; ++i)
        #pragma unroll
        for (int j = 0; j < 4; ++j)
            #pragma unroll
            for (int r = 0; r < 4; ++r)
                C[(long long)(bm + wm + i * 16 + qrow + r) * ldc + bn + wn + j * 16 + col] = acc[i][j][r];

    if (sym) {
        #pragma unroll
        for (int i = 0; i < 4; ++i)
            #pragma unroll
            for (int j = 0; j < 4; ++j) {
                float4 v = make_float4(acc[i][j][0], acc[i][j][1], acc[i][j][2], acc[i][j][3]);
                *(float4*)&C[(long long)(bn + wn + j * 16 + col) * ldc + bm + wm + i * 16 + qrow] = v;
            }
    }
#undef MG_STAGE
#undef MG_COMPUTE
}

// ---------------------------------------------------------------------------
// softmax_vpw: fused stage 3+4. One block = 32 rows.
// Phase A: wave-per-row softmax (verified R4/R5 body) + fp64-refined argmax;
//          weights go to LDS (16B-chunk XOR swizzle: chunk ^= row&7 — both
//          sides are our own ds writes/reads, so swizzle is safe; 2-way free).
// Phase B: vpw GEMM, A from w-LDS, B (vpnT) double-buffered via
//          global_load_lds; fused l2-norm + bf16 + hard-gather epilogue
//          (verified R5). Removes the w_bf 32MB round-trip + 1 dispatch.
// ---------------------------------------------------------------------------
__global__ __launch_bounds__(256) void softmax_vpw(const float* __restrict__ S,
                                                   const float* __restrict__ ks_raw,
                                                   const float* __restrict__ keys_raw,
                                                   const ushort_t* __restrict__ BvT,
                                                   const float* __restrict__ vp_n,
                                                   float* __restrict__ idx_out,
                                                   float* __restrict__ vpw,
                                                   ushort_t* __restrict__ vpw_bf,
                                                   float* __restrict__ vph) {
    const int bm = xcd_swz(blockIdx.x, 512) * 32;

    __shared__ ushort_t Wl[32 * 512];       // 32 KB swizzled weights
    __shared__ ushort_t Bs[2][256 * 32];    // 32 KB B double buffer
    __shared__ float sq[32][4];
    __shared__ float qinv[32];
    __shared__ int   sidx[32];

    const int tid  = threadIdx.x;
    const int wv   = tid >> 6;
    const int lane = tid & 63;

    // ================= phase A: softmax + argmax, rows wv, wv+4, ... =======
    for (int rr = wv; rr < 32; rr += 4) {
        const int row = bm + rr;
        const long long base = (long long)row * NE;
        const float4 va = *(const float4*)(S + base + lane * 4);
        const float4 vb = *(const float4*)(S + base + 256 + lane * 4);

        float m8 = fmaxf(fmaxf(fmaxf(va.x, va.y), fmaxf(va.z, va.w)),
                         fmaxf(fmaxf(vb.x, vb.y), fmaxf(vb.z, vb.w)));
        #pragma unroll
        for (int off = 32; off > 0; off >>= 1) m8 = fmaxf(m8, __shfl_xor(m8, off, 64));
        const float m = m8;

        const float thr = m - 0.02f;   // bf16 GEMM chain bound 0.0156 + slack
        unsigned mask = (va.x >= thr ? 1u : 0u) | (va.y >= thr ? 2u : 0u)
                      | (va.z >= thr ? 4u : 0u) | (va.w >= thr ? 8u : 0u)
                      | (vb.x >= thr ? 16u : 0u) | (vb.y >= thr ? 32u : 0u)
                      | (vb.z >= thr ? 64u : 0u) | (vb.w >= thr ? 128u : 0u);
        ull_t bal = __ballot(mask != 0);

        const float4 af4 = *(const float4*)(ks_raw + (long long)row * DD + lane * 4);
        double best = -1e300; int besti = 0x7fffffff;
        while (bal) {
            const int src = (int)__builtin_ctzll(bal);
            bal &= bal - 1;
            unsigned sm = (unsigned)__shfl((int)mask, src, 64);
            while (sm) {
                const int slot = __builtin_ctz(sm);
                sm &= sm - 1;
                const int c = (slot < 4) ? (src * 4 + slot) : (256 + src * 4 + slot - 4);
                const float4 bf4 = *(const float4*)(keys_raw + (long long)c * DD + lane * 4);
                double dp = (double)af4.x * (double)bf4.x + (double)af4.y * (double)bf4.y
                          + (double)af4.z * (double)bf4.z + (double)af4.w * (double)bf4.w;
                double nb = (double)bf4.x * (double)bf4.x + (double)bf4.y * (double)bf4.y
                          + (double)bf4.z * (double)bf4.z + (double)bf4.w * (double)bf4.w;
                #pragma unroll
                for (int off = 32; off > 0; off >>= 1) {
                    dp += __shfl_xor(dp, off, 64);
                    nb += __shfl_xor(nb, off, 64);
                }
                const double d = dp / sqrt(nb);
                if (d > best || (d == best && c < besti)) { best = d; besti = c; }
            }
        }
        if (lane == 0) { idx_out[row] = (float)besti; sidx[rr] = besti; }

        const float e0 = expf(va.x - m), e1 = expf(va.y - m), e2 = expf(va.z - m), e3 = expf(va.w - m);
        const float e4 = expf(vb.x - m), e5 = expf(vb.y - m), e6 = expf(vb.z - m), e7 = expf(vb.w - m);
        float ssum = ((e0 + e1) + (e2 + e3)) + ((e4 + e5) + (e6 + e7));
        #pragma unroll
        for (int off = 32; off > 0; off >>= 1) ssum += __shfl_xor(ssum, off, 64);
        const float inv = 1.0f / ssum;
        ull_t p0 = (ull_t)f2bf(e0 * inv) | ((ull_t)f2bf(e1 * inv) << 16)
                 | ((ull_t)f2bf(e2 * inv) << 32) | ((ull_t)f2bf(e3 * inv) << 48);
        ull_t p1 = (ull_t)f2bf(e4 * inv) | ((ull_t)f2bf(e5 * inv) << 16)
                 | ((ull_t)f2bf(e6 * inv) << 32) | ((ull_t)f2bf(e7 * inv) << 48);
        // swizzled store: 16B chunk index ^= (row&7); 8B within-chunk offset kept
        {
            char* rowb = (char*)&Wl[rr * 512];
            const int c0 = lane * 4;
            *(ull_t*)(rowb + ((((c0 >> 3) ^ (rr & 7)) << 4) | ((c0 & 7) * 2))) = p0;
            const int c1 = 256 + lane * 4;
            *(ull_t*)(rowb + ((((c1 >> 3) ^ (rr & 7)) << 4) | ((c1 & 7) * 2))) = p1;
        }
    }
    __syncthreads();

    // ================= phase B: vpw GEMM + norm + gather ===================
    const int srow   = lane >> 2;
    const int schunk = (lane & 3) * 8;
    const int wn = wv * 64;             // waves tile the 256 output cols
    const int fr = lane & 15;
    const int fq = (lane >> 4) * 8;

    f32x4 acc[2][4] = {};

#define VB_STAGE(buf, kk)                                                          \
    {                                                                              \
        _Pragma("unroll")                                                          \
        for (int s = 0; s < 4; ++s) {                                              \
            const int rb = (wv * 4 + s) * 16;                                      \
            const ushort_t* gb = BvT + (long long)(rb + srow) * NE + (kk) + schunk; \
            __builtin_amdgcn_global_load_lds((const AS_GLOBAL void*)gb,            \
                (AS_SHARED void*)&Bs[buf][rb * 32], 16, 0, 0);                     \
        }                                                                          \
    }

#define VB_COMPUTE(buf, kb)                                                        \
    {                                                                              \
        bf16x8 afr[2], bfr[4];                                                     \
        _Pragma("unroll")                                                          \
        for (int i = 0; i < 2; ++i) {                                              \
            const int R = i * 16 + fr;                                             \
            afr[i] = *(const bf16x8*)((const char*)Wl +                            \
                     (R * 1024 + (((((kb) + fq) >> 3) ^ (R & 7)) << 4)));          \
        }                                                                          \
        _Pragma("unroll")                                                          \
        for (int j = 0; j < 4; ++j)                                                \
            bfr[j] = *(const bf16x8*)&Bs[buf][(wn + j * 16 + fr) * 32 + fq];       \
        _Pragma("unroll")                                                          \
        for (int i = 0; i < 2; ++i)                                                \
            _Pragma("unroll")                                                      \
            for (int j = 0; j < 4; ++j)                                            \
                acc[i][j] = __builtin_amdgcn_mfma_f32_16x16x32_bf16(afr[i], bfr[j], acc[i][j], 0, 0, 0); \
    }

    VB_STAGE(0, 0);
    __syncthreads();
    int cur = 0;
    for (int k0 = 32; k0 < NE; k0 += 32) {
        VB_STAGE(cur ^ 1, k0);
        VB_COMPUTE(cur, k0 - 32);
        __syncthreads();
        cur ^= 1;
    }
    VB_COMPUTE(cur, NE - 32);

    // fused epilogue: cross-wave row l2-norm (verified R5)
    const int qrow = (lane >> 4) * 4;
    #pragma unroll
    for (int i = 0; i < 2; ++i) {
        #pragma unroll
        for (int r = 0; r < 4; ++r) {
            float s = 0.0f;
            #pragma unroll
            for (int j = 0; j < 4; ++j) { const float a = acc[i][j][r]; s += a * a; }
            #pragma unroll
            for (int msk = 1; msk < 16; msk <<= 1) s += __shfl_xor(s, msk, 64);
            if ((lane & 15) == 0) sq[i * 16 + qrow + r][wv] = s;
        }
    }
    __syncthreads();
    if (tid < 32) {
        const float tot = sq[tid][0] + sq[tid][1] + sq[tid][2] + sq[tid][3];
        qinv[tid] = 1.0f / fmaxf(sqrtf(tot), 1e-12f);
    }
    __syncthreads();

    const int col = lane & 15;
    #pragma unroll
    for (int i = 0; i < 2; ++i)
        #pragma unroll
        for (int r = 0; r < 4; ++r) {
            const int row = i * 16 + qrow + r;
            const float iv = qinv[row];
            #pragma unroll
            for (int j = 0; j < 4; ++j) {
                const float v = acc[i][j][r] * iv;
                const long long o = (long long)(bm + row) * DD + wn + j * 16 + col;
                vpw[o] = v;
                vpw_bf[o] = f2bf(v);
            }
        }

    // hard gather: vph[row] = vp_n[idx[row]] (sidx from phase A — no global trip)
    #pragma unroll 4
    for (int k = 0; k < 32; ++k)
        vph[(long long)(bm + k) * DD + tid] = vp_n[(long long)sidx[k] * DD + tid];
#undef VB_STAGE
#undef VB_COMPUTE
}

// ---------------------------------------------------------------------------
extern "C" void kernel_launch(void* const* d_in, const int* in_sizes, int n_in,
                              void* d_out, int out_size, void* d_ws, size_t ws_size,
                              hipStream_t stream) {
    const float* key_soft = (const float*)d_in[0];   // [16,1024,256]
    const float* keys     = (const float*)d_in[1];   // [512,256]
    const float* vparams  = (const float*)d_in[2];   // [512,256]
    float* out = (float*)d_out;

    // Output layout (flat, return order)
    const long long off0 = 0;                               // encoding_indices [16384]
    const long long off1 = off0 + BT;                       // vparams_w  [16384,256]
    const long long off2 = off1 + (long long)BT * DD;       // vparams_hard
    const long long off3 = off2 + (long long)BT * DD;       // score_vpss [16,1024,1024]
    const long long off4 = off3 + (long long)BB * TT * TT;  // score_vpsh [16384,512]
    const long long off5 = off4 + (long long)BT * NE;       // score_kss [16,1024,1024]
    const long long off6 = off5 + (long long)BB * TT * TT;  // score_ksh [16384,512]

    float* o_idx  = out + off0;
    float* o_vpw  = out + off1;
    float* o_vph  = out + off2;
    float* o_vpss = out + off3;
    float* o_vpsh = out + off4;
    float* o_kss  = out + off5;
    float* o_ksh  = out + off6;

    // ws scratch (~9 MB)
    float*    vp_n      = (float*)d_ws;                           // [512,256] fp32
    ushort_t* vp_n_bf   = (ushort_t*)(vp_n + (long long)NE * DD); // [512,256] bf16
    ushort_t* vpnT_bf   = vp_n_bf + (long long)NE * DD;           // [256,512] bf16
    ushort_t* vpw_bf    = vpnT_bf + (long long)DD * NE;           // [16384,256] bf16
    ushort_t* keys_n_bf = vpw_bf + (long long)BT * DD;            // [512,256] bf16

    // Borrowed d_out region: ksn_bf dead after mega1; o_vpsh written in mega2
    ushort_t* ksn_bf = (ushort_t*)o_vpsh;

    // 1) all normalizations in one dispatch
    prep_all<<<4096 + 2 * NE, 256, 0, stream>>>(
        key_soft, keys, vparams, ksn_bf, keys_n_bf, vp_n, vp_n_bf, vpnT_bf);

    // 2) kss (symmetric, 36x16 tiles) + ksh (512 tiles) in one dispatch
    mega_gemm<<<576 + 512, 256, 0, stream>>>(
        ksn_bf, o_kss, ksn_bf, keys_n_bf, o_ksh);

    // 3+4) fused softmax/argmax + vpw GEMM + norm + gather (grid 512)
    softmax_vpw<<<512, 256, 0, stream>>>(
        o_ksh, key_soft, keys, vpnT_bf, vp_n, o_idx, o_vpw, vpw_bf, o_vph);

    // 5) vpss (symmetric) + vpsh in one dispatch
    mega_gemm<<<576 + 512, 256, 0, stream>>>(
        vpw_bf, o_vpss, vpw_bf, vp_n_bf, o_vpsh);
}

// Round 8
// 311.780 us; speedup vs baseline: 1.0309x; 1.0309x over previous
//
#include <hip/hip_runtime.h>
#include <hip/hip_bf16.h>

// Problem constants
#define BB 16
#define TT 1024
#define DD 256
#define NE 512
#define BT 16384   // BB*TT

typedef unsigned short ushort_t;
typedef unsigned long long ull_t;
typedef __attribute__((ext_vector_type(8))) short bf16x8;
typedef __attribute__((ext_vector_type(4))) float f32x4;

#define AS_GLOBAL __attribute__((address_space(1)))
#define AS_SHARED __attribute__((address_space(3)))

static __device__ __forceinline__ ushort_t f2bf(float f) {
    union { float f; unsigned u; } x; x.f = f;
    unsigned r = x.u + 0x7fffu + ((x.u >> 16) & 1u);   // RNE
    return (ushort_t)(r >> 16);
}

// Bijective XCD-chunked swizzle; REQUIRES grid % 8 == 0.
static __device__ __forceinline__ int xcd_swz(int bid, int grid) {
    const int cpx = grid >> 3;            // chunks per XCD
    return (bid & 7) * cpx + (bid >> 3);
}

// ---------------------------------------------------------------------------
// prep_all: one dispatch for all input normalizations (verified R3-R5).
// ---------------------------------------------------------------------------
__global__ __launch_bounds__(256) void prep_all(const float* __restrict__ ks,
                                                const float* __restrict__ keys,
                                                const float* __restrict__ vparams,
                                                ushort_t* __restrict__ ksn_bf,
                                                ushort_t* __restrict__ keys_n_bf,
                                                float* __restrict__ vp_n,
                                                ushort_t* __restrict__ vp_n_bf,
                                                ushort_t* __restrict__ vpnT_bf) {
    const int bid = blockIdx.x;
    const int t = threadIdx.x;
    if (bid < 4096) {
        const int row  = bid * 4 + (t >> 6);
        const int lane = t & 63;
        const float4 v = *(const float4*)(ks + (long long)row * DD + lane * 4);
        float ss = v.x * v.x + v.y * v.y + v.z * v.z + v.w * v.w;
        #pragma unroll
        for (int off = 32; off > 0; off >>= 1) ss += __shfl_down(ss, off, 64);
        ss = __shfl(ss, 0, 64);
        const float inv = 1.0f / fmaxf(sqrtf(ss), 1e-12f);
        ull_t p =
              (ull_t)f2bf(v.x * inv)
            | ((ull_t)f2bf(v.y * inv) << 16)
            | ((ull_t)f2bf(v.z * inv) << 32)
            | ((ull_t)f2bf(v.w * inv) << 48);
        *(ull_t*)(ksn_bf + (long long)row * DD + lane * 4) = p;
    } else {
        const int b2 = bid - 4096;
        const bool is_keys = (b2 < NE);
        const int rr = is_keys ? b2 : b2 - NE;
        const float* src = (is_keys ? keys : vparams) + (long long)rr * DD;
        const float v = src[t];
        float ss = v * v;
        #pragma unroll
        for (int off = 32; off > 0; off >>= 1) ss += __shfl_down(ss, off, 64);
        __shared__ float partial[4];
        const int wave = t >> 6, lane = t & 63;
        if (lane == 0) partial[wave] = ss;
        __syncthreads();
        __shared__ float s_inv;
        if (t == 0) {
            float tot = partial[0] + partial[1] + partial[2] + partial[3];
            s_inv = 1.0f / fmaxf(sqrtf(tot), 1e-12f);
        }
        __syncthreads();
        const float r = v * s_inv;
        const ushort_t b = f2bf(r);
        if (is_keys) {
            keys_n_bf[(long long)rr * DD + t] = b;
        } else {
            vp_n[(long long)rr * DD + t] = r;
            vp_n_bf[(long long)rr * DD + t] = b;
            vpnT_bf[(long long)t * NE + rr] = b;   // [DD][NE] transpose scatter
        }
    }
}

// ---------------------------------------------------------------------------
// mega_gemm: symmetric batched set + flat set, one dispatch (K-loop verified
// R4/R5). R8: epilogue stages C through LDS for fully-coalesced wide stores:
//   normal: [64][132] f32 chunks -> float4/lane, 512B-contiguous row groups
//   sym   : re-stage transposed [128][66] -> float2/lane, 256B runs
// (previous per-lane scatter emitted 64B segments; ~200MB of C writes total).
// Grid must be 1088 (= 8 * 136).
// ---------------------------------------------------------------------------
__global__ __launch_bounds__(256) void mega_gemm(const ushort_t* __restrict__ Ab,
                                                 float* __restrict__ Cb,
                                                 const ushort_t* __restrict__ Af,
                                                 const ushort_t* __restrict__ Bf,
                                                 float* __restrict__ Cf) {
    const int swz = xcd_swz(blockIdx.x, 1088);
    const ushort_t *A, *Bm;
    float* C;
    int bm, bn, ldc;
    bool sym;
    if (swz < 576) {
        const int z = swz / 36;
        int tt = swz - z * 36;
        int i = 0;
        while (tt >= 8 - i) { tt -= 8 - i; ++i; }
        const int j = i + tt;
        A  = Ab + (long long)z * TT * DD;
        Bm = A;
        C  = Cb + (long long)z * TT * TT;
        bm = i * 128; bn = j * 128; ldc = TT;
        sym = (i != j);
    } else {
        const int f = swz - 576;
        A = Af; Bm = Bf; C = Cf;
        bm = (f >> 2) * 128; bn = (f & 3) * 128; ldc = NE;
        sym = false;
    }

    // 33 KB shared pool: K-loop buffers (32 KB) overlaid with epilogue stage
    __shared__ __align__(16) char smem_all[33792];
    ushort_t (&As)[2][4096] = *reinterpret_cast<ushort_t(*)[2][4096]>(smem_all);
    ushort_t (&Bs)[2][4096] = *reinterpret_cast<ushort_t(*)[2][4096]>(smem_all + 16384);

    const int tid = threadIdx.x;
    const int wv = tid >> 6;
    const int ln = tid & 63;
    const int srow   = ln >> 2;         // 0..15
    const int schunk = (ln & 3) * 8;    // 0,8,16,24
    const int wm = (wv >> 1) * 64;
    const int wn = (wv & 1) * 64;
    const int fr = ln & 15;
    const int fq = (ln >> 4) * 8;

    f32x4 acc[4][4] = {};

#define MG_STAGE(buf, kk)                                                          \
    {                                                                              \
        _Pragma("unroll")                                                          \
        for (int s = 0; s < 2; ++s) {                                              \
            const int ra = wv * 32 + s * 16;                                       \
            const ushort_t* ga = A + (long long)(bm + ra + srow) * DD + (kk) + schunk; \
            __builtin_amdgcn_global_load_lds((const AS_GLOBAL void*)ga,            \
                (AS_SHARED void*)&As[buf][ra * 32], 16, 0, 0);                     \
            const ushort_t* gb = Bm + (long long)(bn + ra + srow) * DD + (kk) + schunk; \
            __builtin_amdgcn_global_load_lds((const AS_GLOBAL void*)gb,            \
                (AS_SHARED void*)&Bs[buf][ra * 32], 16, 0, 0);                     \
        }                                                                          \
    }

#define MG_COMPUTE(buf)                                                            \
    {                                                                              \
        bf16x8 af[4], bfr[4];                                                      \
        _Pragma("unroll")                                                          \
        for (int i = 0; i < 4; ++i)                                                \
            af[i] = *(const bf16x8*)&As[buf][(wm + i * 16 + fr) * 32 + fq];        \
        _Pragma("unroll")                                                          \
        for (int j = 0; j < 4; ++j)                                                \
            bfr[j] = *(const bf16x8*)&Bs[buf][(wn + j * 16 + fr) * 32 + fq];       \
        _Pragma("unroll")                                                          \
        for (int i = 0; i < 4; ++i)                                                \
            _Pragma("unroll")                                                      \
            for (int j = 0; j < 4; ++j)                                            \
                acc[i][j] = __builtin_amdgcn_mfma_f32_16x16x32_bf16(af[i], bfr[j], acc[i][j], 0, 0, 0); \
    }

    MG_STAGE(0, 0);
    __syncthreads();
    int cur = 0;
    #pragma unroll
    for (int k0 = 32; k0 < DD; k0 += 32) {
        MG_STAGE(cur ^ 1, k0);
        MG_COMPUTE(cur);
        __syncthreads();
        cur ^= 1;
    }
    MG_COMPUTE(cur);

    // ---- coalesced epilogue via LDS staging ----
    __syncthreads();                    // K-loop LDS reads complete before reuse
    float* St = (float*)smem_all;       // [64][132] f32 = 33792 B

    const int col16 = ln & 15;
    const int qrow  = (ln >> 4) * 4;

    // normal C block: two 64-row chunks
    #pragma unroll
    for (int c = 0; c < 2; ++c) {
        if ((wv >> 1) == c) {
            #pragma unroll
            for (int i = 0; i < 4; ++i)
                #pragma unroll
                for (int j = 0; j < 4; ++j)
                    #pragma unroll
                    for (int r = 0; r < 4; ++r)
                        St[(i * 16 + qrow + r) * 132 + wn + j * 16 + col16] = acc[i][j][r];
        }
        __syncthreads();
        #pragma unroll
        for (int p = 0; p < 8; ++p) {
            const int row = p * 8 + (tid >> 5);
            const int c4  = (tid & 31) * 4;
            const float4 v = *(const float4*)&St[row * 132 + c4];
            *(float4*)&C[(long long)(bm + c * 64 + row) * ldc + bn + c4] = v;
        }
        __syncthreads();
    }

    // transposed block (symmetric tiles): re-stage transposed, store 256B runs
    if (sym) {
        float* S2 = (float*)smem_all;   // [128][66] f32 = 33792 B
        #pragma unroll
        for (int c = 0; c < 2; ++c) {
            if ((wv >> 1) == c) {
                #pragma unroll
                for (int i = 0; i < 4; ++i)
                    #pragma unroll
                    for (int j = 0; j < 4; ++j)
                        #pragma unroll
                        for (int r = 0; r < 4; ++r)
                            S2[(wn + j * 16 + col16) * 66 + i * 16 + qrow + r] = acc[i][j][r];
            }
            __syncthreads();
            #pragma unroll
            for (int p = 0; p < 16; ++p) {
                const int ctrow = p * 8 + (tid >> 5);
                const int cc    = (tid & 31) * 2;
                const float2 v = *(const float2*)&S2[ctrow * 66 + cc];
                *(float2*)&C[(long long)(bn + ctrow) * ldc + bm + c * 64 + cc] = v;
            }
            __syncthreads();
        }
    }
#undef MG_STAGE
#undef MG_COMPUTE
}

// ---------------------------------------------------------------------------
// softmax_argmax: one WAVE per row (4 rows/block), barrier-free, no LDS.
// Verified R4/R5.
// ---------------------------------------------------------------------------
__global__ __launch_bounds__(256) void softmax_argmax(const float* __restrict__ S,
                                                      const float* __restrict__ ks_raw,
                                                      const float* __restrict__ keys_raw,
                                                      float* __restrict__ idx_out,
                                                      ushort_t* __restrict__ W) {
    const int row  = blockIdx.x * 4 + (threadIdx.x >> 6);
    const int lane = threadIdx.x & 63;
    const long long base = (long long)row * NE;

    const float4 va = *(const float4*)(S + base + lane * 4);
    const float4 vb = *(const float4*)(S + base + 256 + lane * 4);

    float m8 = fmaxf(fmaxf(fmaxf(va.x, va.y), fmaxf(va.z, va.w)),
                     fmaxf(fmaxf(vb.x, vb.y), fmaxf(vb.z, vb.w)));
    #pragma unroll
    for (int off = 32; off > 0; off >>= 1) m8 = fmaxf(m8, __shfl_xor(m8, off, 64));
    const float m = m8;

    const float thr = m - 0.02f;   // bf16 GEMM chain bound 0.0156 + slack
    unsigned mask = (va.x >= thr ? 1u : 0u) | (va.y >= thr ? 2u : 0u)
                  | (va.z >= thr ? 4u : 0u) | (va.w >= thr ? 8u : 0u)
                  | (vb.x >= thr ? 16u : 0u) | (vb.y >= thr ? 32u : 0u)
                  | (vb.z >= thr ? 64u : 0u) | (vb.w >= thr ? 128u : 0u);
    ull_t bal = __ballot(mask != 0);

    const float4 af = *(const float4*)(ks_raw + (long long)row * DD + lane * 4);
    double best = -1e300; int besti = 0x7fffffff;
    while (bal) {
        const int src = (int)__builtin_ctzll(bal);
        bal &= bal - 1;
        unsigned sm = (unsigned)__shfl((int)mask, src, 64);
        while (sm) {
            const int slot = __builtin_ctz(sm);
            sm &= sm - 1;
            const int c = (slot < 4) ? (src * 4 + slot) : (256 + src * 4 + slot - 4);
            const float4 bf4 = *(const float4*)(keys_raw + (long long)c * DD + lane * 4);
            double dp = (double)af.x * (double)bf4.x + (double)af.y * (double)bf4.y
                      + (double)af.z * (double)bf4.z + (double)af.w * (double)bf4.w;
            double nb = (double)bf4.x * (double)bf4.x + (double)bf4.y * (double)bf4.y
                      + (double)bf4.z * (double)bf4.z + (double)bf4.w * (double)bf4.w;
            #pragma unroll
            for (int off = 32; off > 0; off >>= 1) {
                dp += __shfl_xor(dp, off, 64);
                nb += __shfl_xor(nb, off, 64);
            }
            const double d = dp / sqrt(nb);
            if (d > best || (d == best && c < besti)) { best = d; besti = c; }
        }
    }
    if (lane == 0) idx_out[row] = (float)besti;

    const float e0 = expf(va.x - m), e1 = expf(va.y - m), e2 = expf(va.z - m), e3 = expf(va.w - m);
    const float e4 = expf(vb.x - m), e5 = expf(vb.y - m), e6 = expf(vb.z - m), e7 = expf(vb.w - m);
    float ssum = ((e0 + e1) + (e2 + e3)) + ((e4 + e5) + (e6 + e7));
    #pragma unroll
    for (int off = 32; off > 0; off >>= 1) ssum += __shfl_xor(ssum, off, 64);
    const float inv = 1.0f / ssum;
    ull_t p0 = (ull_t)f2bf(e0 * inv) | ((ull_t)f2bf(e1 * inv) << 16)
             | ((ull_t)f2bf(e2 * inv) << 32) | ((ull_t)f2bf(e3 * inv) << 48);
    ull_t p1 = (ull_t)f2bf(e4 * inv) | ((ull_t)f2bf(e5 * inv) << 16)
             | ((ull_t)f2bf(e6 * inv) << 32) | ((ull_t)f2bf(e7 * inv) << 48);
    *(ull_t*)(W + base + lane * 4) = p0;
    *(ull_t*)(W + base + 256 + lane * 4) = p1;
}

// ---------------------------------------------------------------------------
// gemm_vpw_norm: raw = W[BT,NE] @ vpnT[DD,NE]^T with fused l2-normalize,
// bf16 conversion, hard-gather. 32-row tiles, grid 512, 2-phase prefetch.
// Verified R5.
// ---------------------------------------------------------------------------
__global__ __launch_bounds__(256) void gemm_vpw_norm(const ushort_t* __restrict__ Aw,
                                                     const ushort_t* __restrict__ BvT,
                                                     const float* __restrict__ idxf,
                                                     const float* __restrict__ vp_n,
                                                     float* __restrict__ vpw,
                                                     ushort_t* __restrict__ vpw_bf,
                                                     float* __restrict__ vph) {
    const int bm = xcd_swz(blockIdx.x, 512) * 32;

    __shared__ ushort_t As[2][32 * 32];
    __shared__ ushort_t Bs[2][256 * 32];

    const int tid = threadIdx.x;
    const int wv = tid >> 6;
    const int ln = tid & 63;
    const int srow   = ln >> 2;
    const int schunk = (ln & 3) * 8;
    const int wn = wv * 64;             // waves tile columns
    const int fr = ln & 15;
    const int fq = (ln >> 4) * 8;

    f32x4 acc[2][4] = {};

#define VW_STAGE(buf, kk)                                                          \
    {                                                                              \
        _Pragma("unroll")                                                          \
        for (int s = 0; s < 5; ++s) {                                              \
            const int g = wv * 5 + s;                                              \
            if (g < 16) {                                                          \
                const int rb = g * 16;                                             \
                const ushort_t* gb = BvT + (long long)(rb + srow) * NE + (kk) + schunk; \
                __builtin_amdgcn_global_load_lds((const AS_GLOBAL void*)gb,        \
                    (AS_SHARED void*)&Bs[buf][rb * 32], 16, 0, 0);                 \
            } else if (g < 18) {                                                   \
                const int ra = (g - 16) * 16;                                      \
                const ushort_t* ga = Aw + (long long)(bm + ra + srow) * NE + (kk) + schunk; \
                __builtin_amdgcn_global_load_lds((const AS_GLOBAL void*)ga,        \
                    (AS_SHARED void*)&As[buf][ra * 32], 16, 0, 0);                 \
            }                                                                      \
        }                                                                          \
    }

#define VW_COMPUTE(buf)                                                            \
    {                                                                              \
        bf16x8 afr[2], bfr[4];                                                     \
        _Pragma("unroll")                                                          \
        for (int i = 0; i < 2; ++i)                                                \
            afr[i] = *(const bf16x8*)&As[buf][(i * 16 + fr) * 32 + fq];            \
        _Pragma("unroll")                                                          \
        for (int j = 0; j < 4; ++j)                                                \
            bfr[j] = *(const bf16x8*)&Bs[buf][(wn + j * 16 + fr) * 32 + fq];       \
        _Pragma("unroll")                                                          \
        for (int i = 0; i < 2; ++i)                                                \
            _Pragma("unroll")                                                      \
            for (int j = 0; j < 4; ++j)                                            \
                acc[i][j] = __builtin_amdgcn_mfma_f32_16x16x32_bf16(afr[i], bfr[j], acc[i][j], 0, 0, 0); \
    }

    VW_STAGE(0, 0);
    __syncthreads();
    int cur = 0;
    for (int k0 = 32; k0 < NE; k0 += 32) {
        VW_STAGE(cur ^ 1, k0);
        VW_COMPUTE(cur);
        __syncthreads();
        cur ^= 1;
    }
    VW_COMPUTE(cur);

    // ---- fused epilogue: row l2-norm across the 4 waves ----
    __shared__ float sq[32][4];
    __shared__ float inv_s[32];
    __shared__ int   sidx[32];
    const int qrow = (ln >> 4) * 4;
    #pragma unroll
    for (int i = 0; i < 2; ++i) {
        #pragma unroll
        for (int r = 0; r < 4; ++r) {
            float s = 0.0f;
            #pragma unroll
            for (int j = 0; j < 4; ++j) { const float a = acc[i][j][r]; s += a * a; }
            #pragma unroll
            for (int msk = 1; msk < 16; msk <<= 1) s += __shfl_xor(s, msk, 64);
            if ((ln & 15) == 0) sq[i * 16 + qrow + r][wv] = s;
        }
    }
    if (tid < 32) sidx[tid] = (int)idxf[bm + tid];
    __syncthreads();
    if (tid < 32) {
        const float tot = sq[tid][0] + sq[tid][1] + sq[tid][2] + sq[tid][3];
        inv_s[tid] = 1.0f / fmaxf(sqrtf(tot), 1e-12f);
    }
    __syncthreads();

    const int col = ln & 15;
    #pragma unroll
    for (int i = 0; i < 2; ++i)
        #pragma unroll
        for (int r = 0; r < 4; ++r) {
            const int row = i * 16 + qrow + r;
            const float iv = inv_s[row];
            #pragma unroll
            for (int j = 0; j < 4; ++j) {
                const float v = acc[i][j][r] * iv;
                const long long o = (long long)(bm + row) * DD + wn + j * 16 + col;
                vpw[o] = v;
                vpw_bf[o] = f2bf(v);
            }
        }

    // hard gather: vph[row] = vp_n[idx[row]]  (thread t = column t, coalesced)
    #pragma unroll 4
    for (int k = 0; k < 32; ++k) {
        const int grow = bm + k;
        vph[(long long)grow * DD + tid] = vp_n[(long long)sidx[k] * DD + tid];
    }
#undef VW_STAGE
#undef VW_COMPUTE
}

// ---------------------------------------------------------------------------
extern "C" void kernel_launch(void* const* d_in, const int* in_sizes, int n_in,
                              void* d_out, int out_size, void* d_ws, size_t ws_size,
                              hipStream_t stream) {
    const float* key_soft = (const float*)d_in[0];   // [16,1024,256]
    const float* keys     = (const float*)d_in[1];   // [512,256]
    const float* vparams  = (const float*)d_in[2];   // [512,256]
    float* out = (float*)d_out;

    // Output layout (flat, return order)
    const long long off0 = 0;                               // encoding_indices [16384]
    const long long off1 = off0 + BT;                       // vparams_w  [16384,256]
    const long long off2 = off1 + (long long)BT * DD;       // vparams_hard
    const long long off3 = off2 + (long long)BT * DD;       // score_vpss [16,1024,1024]
    const long long off4 = off3 + (long long)BB * TT * TT;  // score_vpsh [16384,512]
    const long long off5 = off4 + (long long)BT * NE;       // score_kss [16,1024,1024]
    const long long off6 = off5 + (long long)BB * TT * TT;  // score_ksh [16384,512]

    float* o_idx  = out + off0;
    float* o_vpw  = out + off1;
    float* o_vph  = out + off2;
    float* o_vpss = out + off3;
    float* o_vpsh = out + off4;
    float* o_kss  = out + off5;
    float* o_ksh  = out + off6;

    // ws scratch (~9 MB)
    float*    vp_n      = (float*)d_ws;                           // [512,256] fp32
    ushort_t* vp_n_bf   = (ushort_t*)(vp_n + (long long)NE * DD); // [512,256] bf16
    ushort_t* vpnT_bf   = vp_n_bf + (long long)NE * DD;           // [256,512] bf16
    ushort_t* vpw_bf    = vpnT_bf + (long long)DD * NE;           // [16384,256] bf16
    ushort_t* keys_n_bf = vpw_bf + (long long)BT * DD;            // [512,256] bf16

    // Borrowed d_out regions (each consumed before its region is overwritten):
    ushort_t* ksn_bf = (ushort_t*)o_vpsh;                         // [16384,256] bf16 (dead after mega1; o_vpsh written in mega2)
    ushort_t* w_bf   = (ushort_t*)(o_vpss + (long long)BT * DD);  // [16384,512] bf16 weights (dead after gemm_vpw_norm; o_vpss written in mega2)

    // 1) all normalizations in one dispatch
    prep_all<<<4096 + 2 * NE, 256, 0, stream>>>(
        key_soft, keys, vparams, ksn_bf, keys_n_bf, vp_n, vp_n_bf, vpnT_bf);

    // 2) kss (symmetric, 36x16 tiles) + ksh (512 tiles) in one dispatch
    mega_gemm<<<576 + 512, 256, 0, stream>>>(
        ksn_bf, o_kss, ksn_bf, keys_n_bf, o_ksh);

    // 3) softmax -> w_bf; argmax with margin-based fp64 refinement (wave/row)
    softmax_argmax<<<BT / 4, 256, 0, stream>>>(o_ksh, key_soft, keys, o_idx, w_bf);

    // 4) vparams_w gemm with fused normalize + bf16 + hard gather (grid 512)
    gemm_vpw_norm<<<512, 256, 0, stream>>>(
        w_bf, vpnT_bf, o_idx, vp_n, o_vpw, vpw_bf, o_vph);

    // 5) vpss (symmetric) + vpsh in one dispatch
    mega_gemm<<<576 + 512, 256, 0, stream>>>(
        vpw_bf, o_vpss, vpw_bf, vp_n_bf, o_vpsh);
}